// Round 8
// baseline (488.089 us; speedup 1.0000x reference)
//
#include <hip/hip_runtime.h>
#include <hip/hip_bf16.h>
#include <math.h>

#define NTOK 8192
#define HD 1024
#define ID 4096
#define NE 8
#define MAXTILES 72
#define SORTT 512
#define TPT (NTOK / SORTT)  // 16 tokens per sort thread

typedef __attribute__((ext_vector_type(8))) short short8;
typedef __attribute__((ext_vector_type(8))) unsigned short ushort8;
typedef __attribute__((ext_vector_type(4))) float floatx4;

__device__ __forceinline__ unsigned short f2bf(float f) {
  unsigned int u = __float_as_uint(f);
  return (unsigned short)((u + 0x7fffu + ((u >> 16) & 1u)) >> 16);
}

__device__ __forceinline__ void async_ld16(const void* g, void* l) {
  __builtin_amdgcn_global_load_lds(
      (const __attribute__((address_space(1))) unsigned int*)g,
      (__attribute__((address_space(3))) unsigned int*)l,
      16, 0, 0);
}

// ---------------- router (standalone; must complete before sort) ---------

__global__ void router_kernel(const float* __restrict__ x, const float* __restrict__ wr,
                              int* __restrict__ eidx, unsigned short* __restrict__ xb) {
  int wave = threadIdx.x >> 6, lane = threadIdx.x & 63;
  int n = blockIdx.x * 4 + wave;
  const float* xr = x + (size_t)n * HD;
  unsigned short* xbr = xb + (size_t)n * HD;
  double acc[NE];
#pragma unroll
  for (int e = 0; e < NE; e++) acc[e] = 0.0;
#pragma unroll
  for (int v = 0; v < 4; v++) {
    int h = (lane + v * 64) * 4;
    float4 xv = *(const float4*)(xr + h);
    ushort4 o;
    o.x = f2bf(xv.x); o.y = f2bf(xv.y); o.z = f2bf(xv.z); o.w = f2bf(xv.w);
    *(ushort4*)(xbr + h) = o;
#pragma unroll
    for (int e = 0; e < NE; e++) {
      float4 wv = *(const float4*)(wr + e * HD + h);
      acc[e] += (double)xv.x * wv.x + (double)xv.y * wv.y +
                (double)xv.z * wv.z + (double)xv.w * wv.w;
    }
  }
#pragma unroll
  for (int m = 32; m >= 1; m >>= 1) {
#pragma unroll
    for (int e = 0; e < NE; e++) acc[e] += __shfl_xor(acc[e], m, 64);
  }
  if (lane == 0) {
    int best = 0; double bv = acc[0];
#pragma unroll
    for (int e = 1; e < NE; e++) if (acc[e] > bv) { bv = acc[e]; best = e; }
    eidx[n] = best;
  }
}

// ---------------- fused transposes + sort (sort = block 0, overlapped) ---
// R12: the 1-block sort used to serialize the whole GPU between launches;
// now it runs concurrently with the 2304 transpose blocks (it only needs
// eidx, complete after router_kernel).  LDS overlaid: transpose tile
// (36.9 KB) and sort arrays (16.4 KB) share one char buffer — different
// blocks, no aliasing hazard.  Transpose = R10's 256x64 tile (512 B
// contiguous writes, 8B-granule XOR swizzle, conflict-free both phases),
// re-indexed for 512 threads (same swizzle math, same per-wave footprint).

__device__ __forceinline__ void transpose_tile256_512(const float* __restrict__ src,
                                                      unsigned short* __restrict__ dst,
                                                      int R, int C, int bx, int by, int bz,
                                                      unsigned short (*t)[72]) {
  size_t bo = (size_t)bz * R * C;
  src += bo; dst += bo;
  int c0 = bx * 64, r0 = by * 256;
  int tid = threadIdx.x;
  int rr = tid >> 4, cc = tid & 15;  // rr 0..31
#pragma unroll
  for (int p = 0; p < 8; p++) {
    int r = p * 32 + rr;
    float4 v = *(const float4*)(src + (size_t)(r0 + r) * C + c0 + cc * 4);
    int gs = cc ^ ((r >> 3) & 15);
    ushort4 o;
    o.x = f2bf(v.x); o.y = f2bf(v.y); o.z = f2bf(v.z); o.w = f2bf(v.w);
    *(ushort4*)&t[r][gs * 4] = o;
  }
  __syncthreads();
  int rc = tid & 31;   // 16B r-chunk: rows rc*8..rc*8+7
  int cb = tid >> 5;   // 0..15
#pragma unroll
  for (int p = 0; p < 4; p++) {
    int c = p * 16 + cb;
    int col = ((c >> 2) ^ (rc & 15)) * 4 + (c & 3);  // inverse of gs swizzle
    ushort8 o;
#pragma unroll
    for (int i = 0; i < 8; i++) o[i] = t[rc * 8 + i][col];
    *(ushort8*)(dst + (size_t)(c0 + c) * R + r0 + rc * 8) = o;
  }
}

__device__ __forceinline__ void sort_body(const int* __restrict__ eidx, int* __restrict__ ntiles,
                                          int* __restrict__ tile_e, int* __restrict__ tile_base,
                                          int* __restrict__ tile_len, int* __restrict__ perm,
                                          char* smem) {
  int (*h)[SORTT] = (int(*)[SORTT])smem;            // 16 KB
  int* off_sh = (int*)(smem + NE * SORTT * 4);      // +32 B
  int* tot = off_sh + NE;                           // +32 B
  int t = threadIdx.x;
  int wave = t >> 6, lane = t & 63;
  const int base = t * TPT;

  int4 e0 = *(const int4*)(eidx + base);
  int4 e1 = *(const int4*)(eidx + base + 4);
  int4 e2 = *(const int4*)(eidx + base + 8);
  int4 e3 = *(const int4*)(eidx + base + 12);
  int ex[TPT] = {e0.x, e0.y, e0.z, e0.w, e1.x, e1.y, e1.z, e1.w,
                 e2.x, e2.y, e2.z, e2.w, e3.x, e3.y, e3.z, e3.w};
  int cnt0 = 0, cnt1 = 0, cnt2 = 0, cnt3 = 0, cnt4 = 0, cnt5 = 0, cnt6 = 0, cnt7 = 0;
#pragma unroll
  for (int i = 0; i < TPT; i++) {
    int e = ex[i];
    cnt0 += (e == 0); cnt1 += (e == 1); cnt2 += (e == 2); cnt3 += (e == 3);
    cnt4 += (e == 4); cnt5 += (e == 5); cnt6 += (e == 6); cnt7 += (e == 7);
  }
  h[0][t] = cnt0; h[1][t] = cnt1; h[2][t] = cnt2; h[3][t] = cnt3;
  h[4][t] = cnt4; h[5][t] = cnt5; h[6][t] = cnt6; h[7][t] = cnt7;
  __syncthreads();

  {
    int e = wave;
    int v[8], s = 0;
#pragma unroll
    for (int i = 0; i < 8; i++) { v[i] = h[e][lane * 8 + i]; s += v[i]; }
    int inc = s;
#pragma unroll
    for (int d = 1; d < 64; d <<= 1) {
      int o = __shfl_up(inc, d, 64);
      if (lane >= d) inc += o;
    }
    int exc = inc - s;
#pragma unroll
    for (int i = 0; i < 8; i++) { h[e][lane * 8 + i] = exc; exc += v[i]; }
    if (lane == 63) tot[e] = inc;
  }
  __syncthreads();

  if (t == 0) {
    int s = 0, tt = 0;
    for (int e = 0; e < NE; e++) {
      off_sh[e] = s;
      int c = tot[e];
      for (int b = 0; b < c; b += 128) {
        tile_e[tt] = e;
        tile_base[tt] = s + b;
        tile_len[tt] = (c - b < 128) ? (c - b) : 128;
        tt++;
      }
      s += c;
    }
    *ntiles = tt;
  }
  __syncthreads();

  int c0c = off_sh[0] + h[0][t], c1c = off_sh[1] + h[1][t];
  int c2c = off_sh[2] + h[2][t], c3c = off_sh[3] + h[3][t];
  int c4c = off_sh[4] + h[4][t], c5c = off_sh[5] + h[5][t];
  int c6c = off_sh[6] + h[6][t], c7c = off_sh[7] + h[7][t];
#pragma unroll
  for (int i = 0; i < TPT; i++) {
    int e = ex[i];
    int pos = c0c;
    pos = (e == 1) ? c1c : pos; pos = (e == 2) ? c2c : pos;
    pos = (e == 3) ? c3c : pos; pos = (e == 4) ? c4c : pos;
    pos = (e == 5) ? c5c : pos; pos = (e == 6) ? c6c : pos;
    pos = (e == 7) ? c7c : pos;
    perm[pos] = base + i;
    c0c += (e == 0); c1c += (e == 1); c2c += (e == 2); c3c += (e == 3);
    c4c += (e == 4); c5c += (e == 5); c6c += (e == 6); c7c += (e == 7);
  }
}

// grid 2305: [0]=sort, [1,2049) w1 transpose, [2049,2305) wo transpose
__global__ __launch_bounds__(512) void tsort_kernel(
    const float* __restrict__ w1, const float* __restrict__ wo,
    unsigned short* __restrict__ w1t, unsigned short* __restrict__ wot,
    const int* __restrict__ eidx, int* __restrict__ ntiles, int* __restrict__ tile_e,
    int* __restrict__ tile_base, int* __restrict__ tile_len, int* __restrict__ perm) {
  __shared__ char smem[256 * 72 * 2];  // 36.9 KB, overlaid
  int b = blockIdx.x;
  if (b == 0) {
    sort_body(eidx, ntiles, tile_e, tile_base, tile_len, perm, smem);
  } else if (b < 2049) {
    int bb = b - 1;
    int e = bb >> 8, rem = bb & 255;
    transpose_tile256_512(w1, w1t, HD, ID, rem & 63, rem >> 6, e,
                          (unsigned short(*)[72])smem);
  } else {
    int bb = b - 2049;
    transpose_tile256_512(wo, wot, ID, HD, bb & 15, bb >> 4, 0,
                          (unsigned short(*)[72])smem);
  }
}

// ---------------- GEMM kernels (R11: R4 internals + refined XCD remap) ---
// 128x128 tile, BK=64, 4 waves (2x2), acc[4][4], 16x16x32 bf16.  LDS
// [row][64] bf16, 16B chunks XOR-swizzled by (row&7): 0 bank conflicts.
// stage -> sync -> compute -> sync; ~3 independent 4-wave blocks/CU.
// XCD remap (t-half x n-quarter): resident B slice 2.1 MB (fits 4 MB L2),
// A-panel shared by the 8 co-located n-blocks.  FETCH 83.7 MB ~ unique.

__global__ __launch_bounds__(256, 2) void ffn1_kernel(
    const unsigned short* __restrict__ xb, const unsigned short* __restrict__ w1t,
    const float* __restrict__ b1, const int* __restrict__ perm,
    const int* __restrict__ ntiles, const int* __restrict__ tile_e,
    const int* __restrict__ tile_base, const int* __restrict__ tile_len,
    unsigned short* __restrict__ interb) {
  // grid 2304 = 8 xcd x 288 slots.  xcd = (t-half(36) x n-quarter(8 nb)).
  int w = blockIdx.x;
  int x = w & 7, s = w >> 3;         // xcd, slot 0..287
  int nq = x & 3, th = x >> 2;       // n-quarter, t-half
  int t = th * 36 + (s >> 3);        // tile 0..71
  if (t >= *ntiles) return;
  int nb = (nq * 8 + (s & 7)) * 128;
  int e = tile_e[t], base = tile_base[t], len = tile_len[t];

  __shared__ unsigned short lA[128 * 64];
  __shared__ unsigned short lB[128 * 64];

  int tid = threadIdx.x;
  int wave = tid >> 6, lane = tid & 63;
  int lr = lane >> 3;              // row-within-8-row-chunk
  int chunk = (lane & 7) ^ lr;     // swizzled 16B chunk selector

  const unsigned short* gA[4];
  const unsigned short* gB[4];
#pragma unroll
  for (int qq = 0; qq < 4; qq++) {
    int c = wave * 4 + qq;
    int tr = c * 8 + lr;
    int token = perm[base + (tr < len ? tr : len - 1)];  // clamp tail (stores masked)
    gA[qq] = xb + (size_t)token * HD + chunk * 8;
    int nr = nb + c * 8 + lr;
    gB[qq] = w1t + ((size_t)e * ID + nr) * HD + chunk * 8;
  }

  floatx4 acc[4][4];
#pragma unroll
  for (int i = 0; i < 4; i++)
#pragma unroll
    for (int j = 0; j < 4; j++) acc[i][j] = (floatx4){0.f, 0.f, 0.f, 0.f};

  int wm = (wave >> 1) * 64, wn = (wave & 1) * 64;
  int c15 = lane & 15, q4 = lane >> 4;

  for (int ko = 0; ko < HD / 64; ko++) {
#pragma unroll
    for (int qq = 0; qq < 4; qq++) {
      int c = wave * 4 + qq;
      async_ld16(gA[qq] + ko * 64, &lA[c * 512]);
      async_ld16(gB[qq] + ko * 64, &lB[c * 512]);
    }
    __syncthreads();
#pragma unroll
    for (int kk = 0; kk < 2; kk++) {
      short8 af[4], bfr[4];
#pragma unroll
      for (int i = 0; i < 4; i++) {
        int m = wm + i * 16 + c15;
        int sa = (kk * 4 + q4) ^ (m & 7);
        af[i] = *(const short8*)&lA[m * 64 + sa * 8];
        int n = wn + i * 16 + c15;
        int sb = (kk * 4 + q4) ^ (n & 7);
        bfr[i] = *(const short8*)&lB[n * 64 + sb * 8];
      }
#pragma unroll
      for (int i = 0; i < 4; i++)
#pragma unroll
        for (int j = 0; j < 4; j++)
          acc[i][j] = __builtin_amdgcn_mfma_f32_16x16x32_bf16(af[i], bfr[j], acc[i][j], 0, 0, 0);
    }
    __syncthreads();
  }

#pragma unroll
  for (int i = 0; i < 4; i++) {
#pragma unroll
    for (int r = 0; r < 4; r++) {
      int tr = wm + i * 16 + q4 * 4 + r;
      if (tr >= len) continue;
      int token = perm[base + tr];
#pragma unroll
      for (int j = 0; j < 4; j++) {
        int col = nb + wn + j * 16 + c15;
        float v = acc[i][j][r] + b1[e * ID + col];
        v = 0.5f * v * (1.0f + erff(v * 0.70710678118654752f));  // exact GELU
        interb[(size_t)token * ID + col] = f2bf(v);
      }
    }
  }
}

// full-K ffn2, fused bias + residual; writes pre-LN y (fp32) to d_out.
__global__ __launch_bounds__(256, 2) void ffn2_kernel(
    const unsigned short* __restrict__ interb, const unsigned short* __restrict__ wot,
    const float* __restrict__ bo, const float* __restrict__ x, float* __restrict__ y) {
  // grid 512 = 8 xcd x 64 slots.  xcd = (m-half(32 tm) x n-quarter(2 nb)):
  // resident wot slice 2.1 MB; interb A-panel shared by co-located blocks.
  int w = blockIdx.x;
  int x8 = w & 7, s = w >> 3;        // xcd, slot 0..63
  int nq = x8 & 3, mh = x8 >> 2;     // n-quarter, m-half
  int tm = mh * 32 + (s >> 1);       // m-tile 0..63
  int nb = (nq * 2 + (s & 1)) * 128; // n-block 0..7

  __shared__ unsigned short lA[128 * 64];
  __shared__ unsigned short lB[128 * 64];

  int tid = threadIdx.x;
  int wave = tid >> 6, lane = tid & 63;
  int lr = lane >> 3;
  int chunk = (lane & 7) ^ lr;

  const unsigned short* gA[4];
  const unsigned short* gB[4];
#pragma unroll
  for (int qq = 0; qq < 4; qq++) {
    int c = wave * 4 + qq;
    int row = tm * 128 + c * 8 + lr;
    gA[qq] = interb + (size_t)row * ID + chunk * 8;
    int nr = nb + c * 8 + lr;
    gB[qq] = wot + (size_t)nr * ID + chunk * 8;
  }

  floatx4 acc[4][4];
#pragma unroll
  for (int i = 0; i < 4; i++)
#pragma unroll
    for (int j = 0; j < 4; j++) acc[i][j] = (floatx4){0.f, 0.f, 0.f, 0.f};

  int wm = (wave >> 1) * 64, wn = (wave & 1) * 64;
  int c15 = lane & 15, q4 = lane >> 4;

  for (int ko = 0; ko < ID / 64; ko++) {
#pragma unroll
    for (int qq = 0; qq < 4; qq++) {
      int c = wave * 4 + qq;
      async_ld16(gA[qq] + ko * 64, &lA[c * 512]);
      async_ld16(gB[qq] + ko * 64, &lB[c * 512]);
    }
    __syncthreads();
#pragma unroll
    for (int kk = 0; kk < 2; kk++) {
      short8 af[4], bfr[4];
#pragma unroll
      for (int i = 0; i < 4; i++) {
        int m = wm + i * 16 + c15;
        int sa = (kk * 4 + q4) ^ (m & 7);
        af[i] = *(const short8*)&lA[m * 64 + sa * 8];
        int n = wn + i * 16 + c15;
        int sb = (kk * 4 + q4) ^ (n & 7);
        bfr[i] = *(const short8*)&lB[n * 64 + sb * 8];
      }
#pragma unroll
      for (int i = 0; i < 4; i++)
#pragma unroll
        for (int j = 0; j < 4; j++)
          acc[i][j] = __builtin_amdgcn_mfma_f32_16x16x32_bf16(af[i], bfr[j], acc[i][j], 0, 0, 0);
    }
    __syncthreads();
  }

#pragma unroll
  for (int i = 0; i < 4; i++) {
#pragma unroll
    for (int r = 0; r < 4; r++) {
      int row = tm * 128 + wm + i * 16 + q4 * 4 + r;
#pragma unroll
      for (int j = 0; j < 4; j++) {
        int col = nb + wn + j * 16 + c15;
        float v = acc[i][j][r] + bo[col] + x[(size_t)row * HD + col];
        y[(size_t)row * HD + col] = v;  // pre-LN y staged in d_out
      }
    }
  }
}

__global__ void ln_kernel(float* __restrict__ y, const float* __restrict__ gamma,
                          const float* __restrict__ beta) {
  int row = blockIdx.x, t = threadIdx.x;
  int lane = t & 63, wave = t >> 6;
  float* yr = y + (size_t)row * HD;
  float4 v = *(const float4*)(yr + t * 4);
  float s = v.x + v.y + v.z + v.w;
  float ss = v.x * v.x + v.y * v.y + v.z * v.z + v.w * v.w;
#pragma unroll
  for (int m = 32; m >= 1; m >>= 1) {
    s += __shfl_xor(s, m, 64);
    ss += __shfl_xor(ss, m, 64);
  }
  __shared__ float sred[4], ssred[4];
  if (lane == 0) { sred[wave] = s; ssred[wave] = ss; }
  __syncthreads();
  s = sred[0] + sred[1] + sred[2] + sred[3];
  ss = ssred[0] + ssred[1] + ssred[2] + ssred[3];
  float mu = s * (1.0f / HD);
  float var = ss * (1.0f / HD) - mu * mu;
  float rs = rsqrtf(var + 1e-12f);
  float4 g = *(const float4*)(gamma + t * 4);
  float4 b = *(const float4*)(beta + t * 4);
  float4 o;
  o.x = (v.x - mu) * rs * g.x + b.x;
  o.y = (v.y - mu) * rs * g.y + b.y;
  o.z = (v.z - mu) * rs * g.z + b.z;
  o.w = (v.w - mu) * rs * g.w + b.w;
  *(float4*)(yr + t * 4) = o;
}

// ---------------- host launcher ----------------

extern "C" void kernel_launch(void* const* d_in, const int* in_sizes, int n_in,
                              void* d_out, int out_size, void* d_ws, size_t ws_size,
                              hipStream_t stream) {
  const float* x     = (const float*)d_in[0];
  const float* wr    = (const float*)d_in[1];
  const float* w1    = (const float*)d_in[2];
  const float* b1    = (const float*)d_in[3];
  const float* wo    = (const float*)d_in[4];
  const float* bo    = (const float*)d_in[5];
  const float* gamma = (const float*)d_in[6];
  const float* beta  = (const float*)d_in[7];
  float* out = (float*)d_out;

  char* p = (char*)d_ws;
  unsigned short* w1t = (unsigned short*)p; p += (size_t)NE * ID * HD * 2;   // 67 MB
  unsigned short* wot = (unsigned short*)p; p += (size_t)HD * ID * 2;        // 8.4 MB
  unsigned short* xb  = (unsigned short*)p; p += (size_t)NTOK * HD * 2;      // 16.8 MB
  unsigned short* interb = (unsigned short*)p; p += (size_t)NTOK * ID * 2;   // 67 MB
  int* eidx = (int*)p; p += (size_t)NTOK * 4;
  int* perm = (int*)p; p += (size_t)NTOK * 4;
  int* ints = (int*)p;
  int* ntiles    = ints;        // 1
  int* tile_e    = ints + 8;    // 72
  int* tile_base = ints + 80;   // 72
  int* tile_len  = ints + 152;  // 72

  router_kernel<<<NTOK / 4, 256, 0, stream>>>(x, wr, eidx, xb);
  tsort_kernel<<<2305, 512, 0, stream>>>(w1, wo, w1t, wot, eidx, ntiles,
                                         tile_e, tile_base, tile_len, perm);
  ffn1_kernel<<<2304, 256, 0, stream>>>(
      xb, w1t, b1, perm, ntiles, tile_e, tile_base, tile_len, interb);
  ffn2_kernel<<<512, 256, 0, stream>>>(interb, wot, bo, x, out);
  ln_kernel<<<NTOK, 256, 0, stream>>>(out, gamma, beta);
}